// Round 10
// baseline (153.740 us; speedup 1.0000x reference)
//
#include <hip/hip_runtime.h>
#include <stdint.h>

#define ALPHA 1.702f
#define LIMIT 7.0f

typedef float f32x4 __attribute__((ext_vector_type(4)));
typedef __bf16 bf16x8 __attribute__((ext_vector_type(8)));

static __device__ __forceinline__ unsigned short f2bf(float f) {
    union { float f; uint32_t u; } v; v.f = f;
    uint32_t u = v.u;
    return (unsigned short)((u + 0x7FFFu + ((u >> 16) & 1u)) >> 16);
}
static __device__ __forceinline__ int imin(int a, int b) { return a < b ? a : b; }

#define GLL16(GP, LP) __builtin_amdgcn_global_load_lds( \
    (const __attribute__((address_space(1))) void*)(GP), \
    (__attribute__((address_space(3))) void*)(LP), 16, 0, 0)

// Conflict-free LDS swizzle (R3-verified: SQ_LDS_BANK_CONFLICT = 0).
static __device__ __forceinline__ int lsw(int row, int kc) {
    return row * 4 + (kc ^ ((row >> 1) & 3));
}

// ---------------------------------------------------------------------------
// prep: blocks [0,6144): fp32->bf16 convert (W1 permuted glu/lin halves).
//       blocks [6144,6400): gate -> per-block routing lists pcnt/gtok/gwt
//       (NO global atomics), aux partials paux[bid][48], out init.
// ---------------------------------------------------------------------------
__global__ __launch_bounds__(256) void prep_kernel(
    const float* __restrict__ w1, const float* __restrict__ w2,
    unsigned short* __restrict__ w1p, unsigned short* __restrict__ w2b,
    const float* __restrict__ x,
    const float* __restrict__ norm_scale,
    const float* __restrict__ gate_w,
    const float* __restrict__ gate_b,
    const float* __restrict__ b2,
    unsigned short* __restrict__ t_bf,
    int* __restrict__ pcnt,       // [256][8]
    int* __restrict__ gtok,       // [256][8][8]
    float* __restrict__ gwt,      // [256][8][8]
    float* __restrict__ paux,     // [256][48]
    float* __restrict__ out)
{
    __shared__ float red[4][48];
    __shared__ int   ltok[8][8];
    __shared__ float lwt[8][8];
    __shared__ int   lcnt[8];
    if (blockIdx.x < 6144) {
        const int i4 = blockIdx.x * 256 + threadIdx.x;
        const int n1 = 1048576;
        if (i4 < n1) {
            const int e = i4 >> 17;
            const int rem = i4 & 131071;
            const int r = rem >> 7;
            const int c = rem & 127;
            const int src = (r < 512) ? (2 * r) : (2 * (r - 512) + 1);
            float4 v = ((const float4*)w1)[(e << 17) + (src << 7) + c];
            ushort4 o = { f2bf(v.x), f2bf(v.y), f2bf(v.z), f2bf(v.w) };
            ((ushort4*)w1p)[i4] = o;
        } else {
            const int i2 = i4 - n1;
            float4 v = ((const float4*)w2)[i2];
            ushort4 o = { f2bf(v.x), f2bf(v.y), f2bf(v.z), f2bf(v.w) };
            ((ushort4*)w2b)[i2] = o;
        }
        return;
    }
    const int bid = blockIdx.x - 6144;
    const int wave = threadIdx.x >> 6;
    const int lane = threadIdx.x & 63;
    if (threadIdx.x < 8) lcnt[threadIdx.x] = 0;
    __syncthreads();

    float accP[8], accI[8], accC[32];
    #pragma unroll
    for (int e = 0; e < 8; ++e) { accP[e] = 0.f; accI[e] = 0.f; }
    #pragma unroll
    for (int i = 0; i < 32; ++i) accC[i] = 0.f;

    #pragma unroll
    for (int it = 0; it < 2; ++it) {
        const int t = bid * 8 + wave * 2 + it;
        const float4* xr = (const float4*)(x + t * 512);
        float4 x0 = xr[lane * 2];
        float4 x1 = xr[lane * 2 + 1];
        float ss = x0.x*x0.x + x0.y*x0.y + x0.z*x0.z + x0.w*x0.w
                 + x1.x*x1.x + x1.y*x1.y + x1.z*x1.z + x1.w*x1.w;
        #pragma unroll
        for (int off = 32; off > 0; off >>= 1) ss += __shfl_xor(ss, off, 64);
        const float rstd = rsqrtf(ss * (1.f / 512.f) + 1e-6f);
        const float4* sr = (const float4*)norm_scale;
        float4 s0 = sr[lane * 2], s1 = sr[lane * 2 + 1];
        float tv[8];
        tv[0] = x0.x * rstd * s0.x; tv[1] = x0.y * rstd * s0.y;
        tv[2] = x0.z * rstd * s0.z; tv[3] = x0.w * rstd * s0.w;
        tv[4] = x1.x * rstd * s1.x; tv[5] = x1.y * rstd * s1.y;
        tv[6] = x1.z * rstd * s1.z; tv[7] = x1.w * rstd * s1.w;
        uint32_t p0 = (uint32_t)f2bf(tv[0]) | ((uint32_t)f2bf(tv[1]) << 16);
        uint32_t p1 = (uint32_t)f2bf(tv[2]) | ((uint32_t)f2bf(tv[3]) << 16);
        uint32_t p2 = (uint32_t)f2bf(tv[4]) | ((uint32_t)f2bf(tv[5]) << 16);
        uint32_t p3 = (uint32_t)f2bf(tv[6]) | ((uint32_t)f2bf(tv[7]) << 16);
        uint4 pk; pk.x = p0; pk.y = p1; pk.z = p2; pk.w = p3;
        ((uint4*)(t_bf + t * 512))[lane] = pk;
        float le[8];
        #pragma unroll
        for (int e = 0; e < 8; ++e) {
            const float4* gw = (const float4*)(gate_w + e * 512);
            float4 g0 = gw[lane * 2], g1 = gw[lane * 2 + 1];
            float d = tv[0]*g0.x + tv[1]*g0.y + tv[2]*g0.z + tv[3]*g0.w
                    + tv[4]*g1.x + tv[5]*g1.y + tv[6]*g1.z + tv[7]*g1.w;
            #pragma unroll
            for (int off = 32; off > 0; off >>= 1) d += __shfl_xor(d, off, 64);
            le[e] = d + gate_b[e];
        }
        float mx = le[0];
        #pragma unroll
        for (int e = 1; e < 8; ++e) mx = fmaxf(mx, le[e]);
        float pe[8], se = 0.f;
        #pragma unroll
        for (int e = 0; e < 8; ++e) { pe[e] = __expf(le[e] - mx); se += pe[e]; }
        const float sinv = 1.f / se;
        #pragma unroll
        for (int e = 0; e < 8; ++e) pe[e] *= sinv;
        unsigned picked = 0;
        int ik[4]; float wk[4];
        #pragma unroll
        for (int k = 0; k < 4; ++k) {
            float bv = -1.f; int bi = 0;
            #pragma unroll
            for (int e = 0; e < 8; ++e)
                if (!(picked & (1u << e)) && pe[e] > bv) { bv = pe[e]; bi = e; }
            ik[k] = bi; wk[k] = bv; picked |= (1u << bi);
        }
        const float winv = 1.f / (wk[0] + wk[1] + wk[2] + wk[3]);
        float nw[4];
        #pragma unroll
        for (int k = 0; k < 4; ++k) nw[k] = wk[k] * winv;
        float ce[8];
        #pragma unroll
        for (int e = 0; e < 8; ++e) {
            float c = 0.f;
            #pragma unroll
            for (int k = 0; k < 4; ++k) c += (ik[k] == e) ? nw[k] : 0.f;
            ce[e] = c;
        }
        if (lane == 0) {
            #pragma unroll
            for (int k = 0; k < 4; ++k) {
                const int e = ik[k];
                const int pos = atomicAdd(&lcnt[e], 1);   // LDS-only atomic
                ltok[e][pos] = t; lwt[e][pos] = nw[k];
            }
        }
        #pragma unroll
        for (int e = 0; e < 8; ++e) { accP[e] += pe[e]; accI[e] += le[e]; }
        #pragma unroll
        for (int k = 0; k < 4; ++k)
            #pragma unroll
            for (int e = 0; e < 8; ++e)
                accC[k * 8 + e] += (ik[k] == e) ? 1.f : 0.f;
        float ov[8];
        ov[0] = x0.x; ov[1] = x0.y; ov[2] = x0.z; ov[3] = x0.w;
        ov[4] = x1.x; ov[5] = x1.y; ov[6] = x1.z; ov[7] = x1.w;
        #pragma unroll
        for (int e = 0; e < 8; ++e) {
            const float4* br = (const float4*)(b2 + e * 512);
            float4 b0 = br[lane * 2], bb1 = br[lane * 2 + 1];
            ov[0] += ce[e] * b0.x; ov[1] += ce[e] * b0.y;
            ov[2] += ce[e] * b0.z; ov[3] += ce[e] * b0.w;
            ov[4] += ce[e] * bb1.x; ov[5] += ce[e] * bb1.y;
            ov[6] += ce[e] * bb1.z; ov[7] += ce[e] * bb1.w;
        }
        float4 o0, o1;
        o0.x = ov[0]; o0.y = ov[1]; o0.z = ov[2]; o0.w = ov[3];
        o1.x = ov[4]; o1.y = ov[5]; o1.z = ov[6]; o1.w = ov[7];
        float4* orow = (float4*)(out + t * 512);
        orow[lane * 2] = o0; orow[lane * 2 + 1] = o1;
    }
    if (lane == 0) {
        #pragma unroll
        for (int e = 0; e < 8; ++e) { red[wave][e] = accP[e]; red[wave][8 + e] = accI[e]; }
        #pragma unroll
        for (int i = 0; i < 32; ++i) red[wave][16 + i] = accC[i];
    }
    __syncthreads();
    if (threadIdx.x < 8) pcnt[bid * 8 + threadIdx.x] = lcnt[threadIdx.x];
    if (threadIdx.x < 64) {
        const int e = threadIdx.x >> 3, i = threadIdx.x & 7;
        if (i < lcnt[e]) {
            gtok[bid * 64 + threadIdx.x] = ltok[e][i];
            gwt[bid * 64 + threadIdx.x]  = lwt[e][i];
        }
    }
    if (threadIdx.x < 48) {
        paux[bid * 48 + threadIdx.x] =
            red[0][threadIdx.x] + red[1][threadIdx.x]
          + red[2][threadIdx.x] + red[3][threadIdx.x];
    }
}

// ---------------------------------------------------------------------------
// Per-block routing preamble: inclusive scan of pcnt[:,e] (256 wide), then
// 128-slot table slot->(token,weight) via binary search. Deterministic —
// gemm1 and gemm2 derive identical slot numbering independently.
// ---------------------------------------------------------------------------
#define ROUTE_PREAMBLE(E, M0, WANT_W)                                        \
    {                                                                        \
        const int v = pcnt[tid * 8 + (E)];                                   \
        sscan[tid] = v;                                                      \
        __syncthreads();                                                     \
        for (int ofs = 1; ofs < 256; ofs <<= 1) {                            \
            int add = (tid >= ofs) ? sscan[tid - ofs] : 0;                   \
            __syncthreads();                                                 \
            sscan[tid] += add;                                               \
            __syncthreads();                                                 \
        }                                                                    \
        cnte = sscan[255];                                                   \
        if ((M0) < cnte) {                                                   \
            if (tid < 128) {                                                 \
                const int s = imin((M0) + tid, cnte - 1);                    \
                int lo = 0, hi = 255;                                        \
                for (int itb = 0; itb < 8; ++itb) {                          \
                    const int mid = (lo + hi) >> 1;                          \
                    if (sscan[mid] > s) hi = mid; else lo = mid + 1;         \
                }                                                            \
                const int b = lo;                                            \
                const int excl = (b > 0) ? sscan[b - 1] : 0;                 \
                const int li = s - excl;                                     \
                stok[tid] = gtok[b * 64 + (E) * 8 + li];                     \
                if (WANT_W) swt[tid] = gwt[b * 64 + (E) * 8 + li];           \
            }                                                                \
            __syncthreads();                                                 \
        }                                                                    \
    }

// ---------------------------------------------------------------------------
// GEMM1 (routed) + swiglu*wcoef. grid 513 = 8e x 16m x 4n (+ block 512 aux).
// XCD = bx&7 = expert. 128x128 tiles, R4 pipelined K-loop.
// ---------------------------------------------------------------------------
__global__ __launch_bounds__(256, 2) void gemm1_swiglu(
    const unsigned short* __restrict__ A,    // t_bf [2048][512]
    const unsigned short* __restrict__ w1p,  // [8][1024][512] glu/lin split
    const float* __restrict__ b1,            // [8][1024] interleaved
    const int* __restrict__ pcnt,            // [256][8]
    const int* __restrict__ gtok,            // [256][8][8]
    const float* __restrict__ gwt,           // [256][8][8]
    unsigned short* __restrict__ As,         // [8][2048][512] compact
    const float* __restrict__ paux,          // [256][48]
    float* __restrict__ aux_out)
{
    if (blockIdx.x == 512) {
        __shared__ float sred[4][48];
        const int wv = threadIdx.x >> 6, ln = threadIdx.x & 63;
        if (ln < 48) {
            float s = 0.f;
            for (int b = 0; b < 64; ++b) s += paux[(wv * 64 + b) * 48 + ln];
            sred[wv][ln] = s;
        }
        __syncthreads();
        if (threadIdx.x == 0) {
            float imp[8], sl = 0.f;
            #pragma unroll
            for (int e = 0; e < 8; ++e) {
                float a0 = sred[0][e] + sred[1][e] + sred[2][e] + sred[3][e];
                float P = a0 * (1.f / 2048.f);
                imp[e] = sred[0][8+e] + sred[1][8+e] + sred[2][8+e] + sred[3][8+e];
                float c0 = sred[0][16+e] + sred[1][16+e] + sred[2][16+e] + sred[3][16+e];
                float c1 = sred[0][24+e] + sred[1][24+e] + sred[2][24+e] + sred[3][24+e];
                float c2 = sred[0][32+e] + sred[1][32+e] + sred[2][32+e] + sred[3][32+e];
                float c3 = sred[0][40+e] + sred[1][40+e] + sred[2][40+e] + sred[3][40+e];
                float D = (16.f * c0 + 8.f * c1 + 4.f * c2 + 2.f * c3) * (1.f / 8192.f);
                sl += P * D;
            }
            float loss_load = 0.01f * 8.f * sl;
            float mean = 0.f;
            #pragma unroll
            for (int e = 0; e < 8; ++e) mean += imp[e];
            mean *= 0.125f;
            float var = 0.f;
            #pragma unroll
            for (int e = 0; e < 8; ++e) { float d = imp[e] - mean; var += d * d; }
            var *= (1.f / 7.f);
            float cv = sqrtf(var) / (mean + 1e-6f);
            *aux_out = loss_load + 0.01f * cv * cv;
        }
        return;
    }
    __shared__ unsigned short tA[2][4096];
    __shared__ unsigned short tBg[2][4096];
    __shared__ unsigned short tBl[2][4096];
    __shared__ int sscan[256];
    __shared__ int stok[128];
    __shared__ float swt[128];
    const int bx = blockIdx.x;
    const int tid = threadIdx.x;
    const int e = bx & 7;
    const int slot = bx >> 3;
    const int tile_m = slot >> 2, tile_n = slot & 3;
    const int m0 = tile_m * 128, np = tile_n * 128;

    int cnte;
    ROUTE_PREAMBLE(e, m0, 1);
    if (m0 >= cnte) return;

    const int lane = tid & 63, wave = tid >> 6;
    const int wm = (wave & 1) * 64, wn = (wave >> 1) * 64;
    const int quad = lane >> 4, l16 = lane & 15;
    const int srow = tid >> 2;
    const int soff = ((tid & 3) ^ ((tid >> 3) & 3)) * 8;

    const int tok0 = stok[srow];
    const int tok1 = stok[64 + srow];
    float cw[4][4];
    #pragma unroll
    for (int i = 0; i < 4; ++i)
        #pragma unroll
        for (int r = 0; r < 4; ++r)
            cw[i][r] = swt[wm + i * 16 + quad * 4 + r];

    const unsigned short* Ar0 = A + tok0 * 512 + soff;
    const unsigned short* Ar1 = A + tok1 * 512 + soff;
    const unsigned short* Bg = w1p + (e * 1024 + np) * 512;
    const unsigned short* Bg0 = Bg + srow * 512 + soff;
    const unsigned short* Bg1 = Bg + (64 + srow) * 512 + soff;
    const unsigned short* Bl0 = Bg0 + 512 * 512;
    const unsigned short* Bl1 = Bg1 + 512 * 512;

    int rA[4], rB[4];
    #pragma unroll
    for (int i = 0; i < 4; ++i) {
        rA[i] = lsw(wm + i * 16 + l16, quad) * 8;
        rB[i] = lsw(wn + i * 16 + l16, quad) * 8;
    }

    f32x4 accG[4][4], accL[4][4];
    #pragma unroll
    for (int i = 0; i < 4; ++i)
        #pragma unroll
        for (int j = 0; j < 4; ++j) {
            f32x4 z = {0.f, 0.f, 0.f, 0.f};
            accG[i][j] = z; accL[i][j] = z;
        }

#define STAGE1(s, k0) do { \
    GLL16(Ar0 + (k0), tA[s] + tid * 8); \
    GLL16(Ar1 + (k0), tA[s] + (tid + 256) * 8); \
    GLL16(Bg0 + (k0), tBg[s] + tid * 8); \
    GLL16(Bg1 + (k0), tBg[s] + (tid + 256) * 8); \
    GLL16(Bl0 + (k0), tBl[s] + tid * 8); \
    GLL16(Bl1 + (k0), tBl[s] + (tid + 256) * 8); \
} while (0)

    STAGE1(0, 0);
    STAGE1(1, 32);
    #pragma unroll
    for (int kt = 0; kt < 16; ++kt) {
        const int cur = kt & 1;
        if (kt < 15) asm volatile("s_waitcnt vmcnt(6)" ::: "memory");
        else         asm volatile("s_waitcnt vmcnt(0)" ::: "memory");
        asm volatile("s_barrier" ::: "memory");
        bf16x8 af[4], bg[4], bl[4];
        #pragma unroll
        for (int i = 0; i < 4; ++i) {
            af[i] = *(const bf16x8*)(tA[cur] + rA[i]);
            bg[i] = *(const bf16x8*)(tBg[cur] + rB[i]);
            bl[i] = *(const bf16x8*)(tBl[cur] + rB[i]);
        }
        asm volatile("s_waitcnt lgkmcnt(0)" ::: "memory");
        asm volatile("s_barrier" ::: "memory");
        if (kt < 14) STAGE1(cur, (kt + 2) * 32);
        #pragma unroll
        for (int i = 0; i < 4; ++i)
            #pragma unroll
            for (int j = 0; j < 4; ++j) {
                accG[i][j] = __builtin_amdgcn_mfma_f32_16x16x32_bf16(af[i], bg[j], accG[i][j], 0, 0, 0);
                accL[i][j] = __builtin_amdgcn_mfma_f32_16x16x32_bf16(af[i], bl[j], accL[i][j], 0, 0, 0);
            }
    }
#undef STAGE1

    #pragma unroll
    for (int j = 0; j < 4; ++j) {
        const int colp = np + wn + j * 16 + l16;
        const float bgv = b1[e * 1024 + 2 * colp];
        const float blv = b1[e * 1024 + 2 * colp + 1];
        #pragma unroll
        for (int i = 0; i < 4; ++i) {
            const int sb = m0 + wm + i * 16 + quad * 4;
            #pragma unroll
            for (int r = 0; r < 4; ++r) {
                const int s = sb + r;
                if (s < cnte) {
                    float g2 = fminf(fmaxf(accG[i][j][r] + bgv, -LIMIT), LIMIT);
                    float l2 = fminf(fmaxf(accL[i][j][r] + blv, -LIMIT), LIMIT);
                    float a = g2 / (1.f + __expf(-ALPHA * g2)) + l2 + 1.f;
                    a *= cw[i][r];
                    As[e * 1048576 + s * 512 + colp] = f2bf(a);
                }
            }
        }
    }
}

// ---------------------------------------------------------------------------
// GEMM2 (routed): grid 512 = 8e x 16m x 4n, XCD = e. Compact As rows,
// scatter fp32 atomicAdd into pre-initialized out. Poisoned As tail rows are
// finite bf16 garbage; rows independent in MFMA, masked at scatter.
// ---------------------------------------------------------------------------
__global__ __launch_bounds__(256, 2) void gemm2(
    const unsigned short* __restrict__ As,  // [8][2048][512] compact
    const unsigned short* __restrict__ w2b, // [8][512][512]
    const int* __restrict__ pcnt,           // [256][8]
    const int* __restrict__ gtok,           // [256][8][8]
    const float* __restrict__ gwt,          // [256][8][8] (unused; macro compat)
    float* __restrict__ out)                // [2048][512]
{
    __shared__ unsigned short tA[2][4096];
    __shared__ unsigned short tB[2][4096];
    __shared__ int sscan[256];
    __shared__ int stok[128];
    __shared__ float swt[128];
    const int bx = blockIdx.x;
    const int tid = threadIdx.x;
    const int e = bx & 7;
    const int slot = bx >> 3;
    const int tile_m = slot >> 2, tile_n = slot & 3;
    const int m0 = tile_m * 128, n0 = tile_n * 128;

    int cnte;
    ROUTE_PREAMBLE(e, m0, 0);
    if (m0 >= cnte) return;

    const int lane = tid & 63, wave = tid >> 6;
    const int wm = (wave & 1) * 64, wn = (wave >> 1) * 64;
    const int quad = lane >> 4, l16 = lane & 15;
    const int srow = tid >> 2;
    const int soff = ((tid & 3) ^ ((tid >> 3) & 3)) * 8;

    int rtok[4][4];
    #pragma unroll
    for (int i = 0; i < 4; ++i)
        #pragma unroll
        for (int r = 0; r < 4; ++r)
            rtok[i][r] = stok[wm + i * 16 + quad * 4 + r];

    const unsigned short* Ar0 = As + e * 1048576 + (m0 + srow) * 512 + soff;
    const unsigned short* Ar1 = As + e * 1048576 + (m0 + 64 + srow) * 512 + soff;
    const unsigned short* Bb  = w2b + e * 262144;
    const unsigned short* Br0 = Bb + (n0 + srow) * 512 + soff;
    const unsigned short* Br1 = Bb + (n0 + 64 + srow) * 512 + soff;

    int rA[4], rB[4];
    #pragma unroll
    for (int i = 0; i < 4; ++i) {
        rA[i] = lsw(wm + i * 16 + l16, quad) * 8;
        rB[i] = lsw(wn + i * 16 + l16, quad) * 8;
    }

    f32x4 acc[4][4];
    #pragma unroll
    for (int i = 0; i < 4; ++i)
        #pragma unroll
        for (int j = 0; j < 4; ++j) { f32x4 z = {0.f, 0.f, 0.f, 0.f}; acc[i][j] = z; }

#define STAGE2(s, k0) do { \
    GLL16(Ar0 + (k0), tA[s] + tid * 8); \
    GLL16(Ar1 + (k0), tA[s] + (tid + 256) * 8); \
    GLL16(Br0 + (k0), tB[s] + tid * 8); \
    GLL16(Br1 + (k0), tB[s] + (tid + 256) * 8); \
} while (0)

    STAGE2(0, 0);
    STAGE2(1, 32);
    #pragma unroll
    for (int kt = 0; kt < 16; ++kt) {
        const int cur = kt & 1;
        if (kt < 15) asm volatile("s_waitcnt vmcnt(4)" ::: "memory");
        else         asm volatile("s_waitcnt vmcnt(0)" ::: "memory");
        asm volatile("s_barrier" ::: "memory");
        bf16x8 af[4], bf[4];
        #pragma unroll
        for (int i = 0; i < 4; ++i) {
            af[i] = *(const bf16x8*)(tA[cur] + rA[i]);
            bf[i] = *(const bf16x8*)(tB[cur] + rB[i]);
        }
        asm volatile("s_waitcnt lgkmcnt(0)" ::: "memory");
        asm volatile("s_barrier" ::: "memory");
        if (kt < 14) STAGE2(cur, (kt + 2) * 32);
        #pragma unroll
        for (int i = 0; i < 4; ++i)
            #pragma unroll
            for (int j = 0; j < 4; ++j)
                acc[i][j] = __builtin_amdgcn_mfma_f32_16x16x32_bf16(af[i], bf[j], acc[i][j], 0, 0, 0);
    }
#undef STAGE2

    #pragma unroll
    for (int i = 0; i < 4; ++i) {
        const int sb = m0 + wm + i * 16 + quad * 4;
        #pragma unroll
        for (int r = 0; r < 4; ++r) {
            const int s = sb + r;
            if (s < cnte) {
                const int tok = rtok[i][r];
                #pragma unroll
                for (int j = 0; j < 4; ++j) {
                    const int col = n0 + wn + j * 16 + l16;
                    atomicAdd(&out[tok * 512 + col], acc[i][j][r]);
                }
            }
        }
    }
}

// ---------------------------------------------------------------------------
extern "C" void kernel_launch(void* const* d_in, const int* in_sizes, int n_in,
                              void* d_out, int out_size, void* d_ws, size_t ws_size,
                              hipStream_t stream)
{
    (void)in_sizes; (void)n_in; (void)out_size; (void)ws_size;
    const float* x          = (const float*)d_in[0];
    const float* norm_scale = (const float*)d_in[1];
    const float* gate_w     = (const float*)d_in[2];
    const float* gate_b     = (const float*)d_in[3];
    const float* mlp1_w     = (const float*)d_in[4];
    const float* mlp1_b     = (const float*)d_in[5];
    const float* mlp2_w     = (const float*)d_in[6];
    const float* mlp2_b     = (const float*)d_in[7];
    float* out = (float*)d_out;

    char* ws = (char*)d_ws;
    unsigned short* w1p   = (unsigned short*)(ws);              // 8,388,608 B
    unsigned short* w2b   = (unsigned short*)(ws + 8388608);    // 4,194,304 B
    unsigned short* tbf   = (unsigned short*)(ws + 12582912);   // 2,097,152 B
    unsigned short* As    = (unsigned short*)(ws + 14680064);   // 16,777,216 B
    float*          paux  = (float*)(ws + 31457280);            // 49,152 B
    int*            pcnt  = (int*)(ws + 31506432);              // 8,192 B
    int*            gtok  = (int*)(ws + 31514624);              // 65,536 B
    float*          gwt   = (float*)(ws + 31580160);            // 65,536 B

    prep_kernel<<<6400, 256, 0, stream>>>(mlp1_w, mlp2_w, w1p, w2b,
                                          x, norm_scale, gate_w, gate_b, mlp2_b,
                                          tbf, pcnt, gtok, gwt, paux, out);
    gemm1_swiglu<<<513, 256, 0, stream>>>(tbf, w1p, mlp1_b, pcnt, gtok, gwt,
                                          As, paux, out + 2048 * 512);
    gemm2<<<512, 256, 0, stream>>>(As, w2b, pcnt, gtok, gwt, out);
}

// Round 11
// 144.210 us; speedup vs baseline: 1.0661x; 1.0661x over previous
//
#include <hip/hip_runtime.h>
#include <stdint.h>

#define ALPHA 1.702f
#define LIMIT 7.0f

typedef float f32x4 __attribute__((ext_vector_type(4)));
typedef __bf16 bf16x8 __attribute__((ext_vector_type(8)));

static __device__ __forceinline__ unsigned short f2bf(float f) {
    union { float f; uint32_t u; } v; v.f = f;
    uint32_t u = v.u;
    return (unsigned short)((u + 0x7FFFu + ((u >> 16) & 1u)) >> 16);
}
static __device__ __forceinline__ int imin(int a, int b) { return a < b ? a : b; }

#define GLL16(GP, LP) __builtin_amdgcn_global_load_lds( \
    (const __attribute__((address_space(1))) void*)(GP), \
    (__attribute__((address_space(3))) void*)(LP), 16, 0, 0)

// Conflict-free LDS swizzle (R3-verified: SQ_LDS_BANK_CONFLICT = 0).
static __device__ __forceinline__ int lsw(int row, int kc) {
    return row * 4 + (kc ^ ((row >> 1) & 3));
}

// ---------------------------------------------------------------------------
// prep: blocks [0,4096): fp32->bf16 W1 convert (glu/lin split). blocks
//       [4096,4352): gate -> t_bf, per-block lists pcnt/gtok/gwt, per-token
//       esel/cw4, aux partials. NO out init (combine writes out once).
// ---------------------------------------------------------------------------
__global__ __launch_bounds__(256) void prep_kernel(
    const float* __restrict__ w1,
    unsigned short* __restrict__ w1p,
    const float* __restrict__ x,
    const float* __restrict__ norm_scale,
    const float* __restrict__ gate_w,
    const float* __restrict__ gate_b,
    unsigned short* __restrict__ t_bf,
    int* __restrict__ pcnt,        // [256][8]
    int* __restrict__ gtok,        // [256][8][8]
    float* __restrict__ gwt,       // [256][8][8]
    unsigned int* __restrict__ esel, // [2048] packed 4x expert id
    float* __restrict__ cw4,       // [2048][4]
    float* __restrict__ paux)      // [256][48]
{
    __shared__ float red[4][48];
    __shared__ int   ltok[8][8];
    __shared__ float lwt[8][8];
    __shared__ int   lcnt[8];
    if (blockIdx.x < 4096) {
        const int i4 = blockIdx.x * 256 + threadIdx.x;   // < 1048576
        const int e = i4 >> 17;
        const int rem = i4 & 131071;
        const int r = rem >> 7;
        const int c = rem & 127;
        const int src = (r < 512) ? (2 * r) : (2 * (r - 512) + 1);
        float4 v = ((const float4*)w1)[(e << 17) + (src << 7) + c];
        ushort4 o = { f2bf(v.x), f2bf(v.y), f2bf(v.z), f2bf(v.w) };
        ((ushort4*)w1p)[i4] = o;
        return;
    }
    const int bid = blockIdx.x - 4096;
    const int wave = threadIdx.x >> 6;
    const int lane = threadIdx.x & 63;
    if (threadIdx.x < 8) lcnt[threadIdx.x] = 0;
    __syncthreads();

    float accP[8], accI[8], accC[32];
    #pragma unroll
    for (int e = 0; e < 8; ++e) { accP[e] = 0.f; accI[e] = 0.f; }
    #pragma unroll
    for (int i = 0; i < 32; ++i) accC[i] = 0.f;

    #pragma unroll
    for (int it = 0; it < 2; ++it) {
        const int t = bid * 8 + wave * 2 + it;
        const float4* xr = (const float4*)(x + t * 512);
        float4 x0 = xr[lane * 2];
        float4 x1 = xr[lane * 2 + 1];
        float ss = x0.x*x0.x + x0.y*x0.y + x0.z*x0.z + x0.w*x0.w
                 + x1.x*x1.x + x1.y*x1.y + x1.z*x1.z + x1.w*x1.w;
        #pragma unroll
        for (int off = 32; off > 0; off >>= 1) ss += __shfl_xor(ss, off, 64);
        const float rstd = rsqrtf(ss * (1.f / 512.f) + 1e-6f);
        const float4* sr = (const float4*)norm_scale;
        float4 s0 = sr[lane * 2], s1 = sr[lane * 2 + 1];
        float tv[8];
        tv[0] = x0.x * rstd * s0.x; tv[1] = x0.y * rstd * s0.y;
        tv[2] = x0.z * rstd * s0.z; tv[3] = x0.w * rstd * s0.w;
        tv[4] = x1.x * rstd * s1.x; tv[5] = x1.y * rstd * s1.y;
        tv[6] = x1.z * rstd * s1.z; tv[7] = x1.w * rstd * s1.w;
        uint32_t p0 = (uint32_t)f2bf(tv[0]) | ((uint32_t)f2bf(tv[1]) << 16);
        uint32_t p1 = (uint32_t)f2bf(tv[2]) | ((uint32_t)f2bf(tv[3]) << 16);
        uint32_t p2 = (uint32_t)f2bf(tv[4]) | ((uint32_t)f2bf(tv[5]) << 16);
        uint32_t p3 = (uint32_t)f2bf(tv[6]) | ((uint32_t)f2bf(tv[7]) << 16);
        uint4 pk; pk.x = p0; pk.y = p1; pk.z = p2; pk.w = p3;
        ((uint4*)(t_bf + t * 512))[lane] = pk;
        float le[8];
        #pragma unroll
        for (int e = 0; e < 8; ++e) {
            const float4* gw = (const float4*)(gate_w + e * 512);
            float4 g0 = gw[lane * 2], g1 = gw[lane * 2 + 1];
            float d = tv[0]*g0.x + tv[1]*g0.y + tv[2]*g0.z + tv[3]*g0.w
                    + tv[4]*g1.x + tv[5]*g1.y + tv[6]*g1.z + tv[7]*g1.w;
            #pragma unroll
            for (int off = 32; off > 0; off >>= 1) d += __shfl_xor(d, off, 64);
            le[e] = d + gate_b[e];
        }
        float mx = le[0];
        #pragma unroll
        for (int e = 1; e < 8; ++e) mx = fmaxf(mx, le[e]);
        float pe[8], se = 0.f;
        #pragma unroll
        for (int e = 0; e < 8; ++e) { pe[e] = __expf(le[e] - mx); se += pe[e]; }
        const float sinv = 1.f / se;
        #pragma unroll
        for (int e = 0; e < 8; ++e) pe[e] *= sinv;
        unsigned picked = 0;
        int ik[4]; float wk[4];
        #pragma unroll
        for (int k = 0; k < 4; ++k) {
            float bv = -1.f; int bi = 0;
            #pragma unroll
            for (int e = 0; e < 8; ++e)
                if (!(picked & (1u << e)) && pe[e] > bv) { bv = pe[e]; bi = e; }
            ik[k] = bi; wk[k] = bv; picked |= (1u << bi);
        }
        const float winv = 1.f / (wk[0] + wk[1] + wk[2] + wk[3]);
        float nw[4];
        #pragma unroll
        for (int k = 0; k < 4; ++k) nw[k] = wk[k] * winv;
        if (lane == 0) {
            #pragma unroll
            for (int k = 0; k < 4; ++k) {
                const int e = ik[k];
                const int pos = atomicAdd(&lcnt[e], 1);   // LDS atomic
                ltok[e][pos] = t; lwt[e][pos] = nw[k];
            }
            esel[t] = (unsigned)ik[0] | ((unsigned)ik[1] << 8)
                    | ((unsigned)ik[2] << 16) | ((unsigned)ik[3] << 24);
            float4 cwv; cwv.x = nw[0]; cwv.y = nw[1]; cwv.z = nw[2]; cwv.w = nw[3];
            ((float4*)cw4)[t] = cwv;
        }
        #pragma unroll
        for (int e = 0; e < 8; ++e) { accP[e] += pe[e]; accI[e] += le[e]; }
        #pragma unroll
        for (int k = 0; k < 4; ++k)
            #pragma unroll
            for (int e = 0; e < 8; ++e)
                accC[k * 8 + e] += (ik[k] == e) ? 1.f : 0.f;
    }
    if (lane == 0) {
        #pragma unroll
        for (int e = 0; e < 8; ++e) { red[wave][e] = accP[e]; red[wave][8 + e] = accI[e]; }
        #pragma unroll
        for (int i = 0; i < 32; ++i) red[wave][16 + i] = accC[i];
    }
    __syncthreads();
    if (threadIdx.x < 8) pcnt[bid * 8 + threadIdx.x] = lcnt[threadIdx.x];
    if (threadIdx.x < 64) {
        const int e = threadIdx.x >> 3, i = threadIdx.x & 7;
        if (i < lcnt[e]) {
            gtok[bid * 64 + threadIdx.x] = ltok[e][i];
            gwt[bid * 64 + threadIdx.x]  = lwt[e][i];
        }
    }
    if (threadIdx.x < 48) {
        paux[bid * 48 + threadIdx.x] =
            red[0][threadIdx.x] + red[1][threadIdx.x]
          + red[2][threadIdx.x] + red[3][threadIdx.x];
    }
}

// ---------------------------------------------------------------------------
// GEMM1 (routed) + swiglu*wcoef. grid 2561:
//   blocks 0..511: 8e x 16m x 4n compute tiles (XCD = e), publish cntg and
//                  invslot (tile_n==0), write compact As.
//   block 512: aux loss. blocks 513..2560: W2 fp32->bf16 convert (runs in
//   gemm1's CU/BW shadow; gemm2 launch waits for whole grid).
// ---------------------------------------------------------------------------
__global__ __launch_bounds__(256, 2) void gemm1_swiglu(
    const unsigned short* __restrict__ A,    // t_bf [2048][512]
    const unsigned short* __restrict__ w1p,  // [8][1024][512] glu/lin split
    const float* __restrict__ b1,            // [8][1024] interleaved
    const int* __restrict__ pcnt,            // [256][8]
    const int* __restrict__ gtok,            // [256][8][8]
    const float* __restrict__ gwt,           // [256][8][8]
    unsigned short* __restrict__ As,         // [8][2048][512] compact
    int* __restrict__ cntg,                  // [8]
    int* __restrict__ invslot,               // [8][2048] token -> slot
    const float* __restrict__ paux,          // [256][48]
    float* __restrict__ aux_out,
    const float* __restrict__ w2,            // fp32 [8][512][512]
    unsigned short* __restrict__ w2b)        // bf16 out
{
    if (blockIdx.x == 512) {
        __shared__ float sred[4][48];
        const int wv = threadIdx.x >> 6, ln = threadIdx.x & 63;
        if (ln < 48) {
            float s = 0.f;
            for (int b = 0; b < 64; ++b) s += paux[(wv * 64 + b) * 48 + ln];
            sred[wv][ln] = s;
        }
        __syncthreads();
        if (threadIdx.x == 0) {
            float imp[8], sl = 0.f;
            #pragma unroll
            for (int e = 0; e < 8; ++e) {
                float a0 = sred[0][e] + sred[1][e] + sred[2][e] + sred[3][e];
                float P = a0 * (1.f / 2048.f);
                imp[e] = sred[0][8+e] + sred[1][8+e] + sred[2][8+e] + sred[3][8+e];
                float c0 = sred[0][16+e] + sred[1][16+e] + sred[2][16+e] + sred[3][16+e];
                float c1 = sred[0][24+e] + sred[1][24+e] + sred[2][24+e] + sred[3][24+e];
                float c2 = sred[0][32+e] + sred[1][32+e] + sred[2][32+e] + sred[3][32+e];
                float c3 = sred[0][40+e] + sred[1][40+e] + sred[2][40+e] + sred[3][40+e];
                float D = (16.f * c0 + 8.f * c1 + 4.f * c2 + 2.f * c3) * (1.f / 8192.f);
                sl += P * D;
            }
            float loss_load = 0.01f * 8.f * sl;
            float mean = 0.f;
            #pragma unroll
            for (int e = 0; e < 8; ++e) mean += imp[e];
            mean *= 0.125f;
            float var = 0.f;
            #pragma unroll
            for (int e = 0; e < 8; ++e) { float d = imp[e] - mean; var += d * d; }
            var *= (1.f / 7.f);
            float cv = sqrtf(var) / (mean + 1e-6f);
            *aux_out = loss_load + 0.01f * cv * cv;
        }
        return;
    }
    if (blockIdx.x > 512) {
        const int i2 = (blockIdx.x - 513) * 256 + threadIdx.x;   // < 524288
        float4 v = ((const float4*)w2)[i2];
        ushort4 o = { f2bf(v.x), f2bf(v.y), f2bf(v.z), f2bf(v.w) };
        ((ushort4*)w2b)[i2] = o;
        return;
    }
    __shared__ unsigned short tA[2][4096];
    __shared__ unsigned short tBg[2][4096];
    __shared__ unsigned short tBl[2][4096];
    __shared__ int sscan[256];
    __shared__ int stok[128];
    __shared__ float swt[128];
    const int bx = blockIdx.x;
    const int tid = threadIdx.x;
    const int e = bx & 7;
    const int slot = bx >> 3;
    const int tile_m = slot >> 2, tile_n = slot & 3;
    const int m0 = tile_m * 128, np = tile_n * 128;

    // route preamble: scan pcnt[:,e], build 128-slot token/weight table
    {
        const int v = pcnt[tid * 8 + e];
        sscan[tid] = v;
        __syncthreads();
        for (int ofs = 1; ofs < 256; ofs <<= 1) {
            int add = (tid >= ofs) ? sscan[tid - ofs] : 0;
            __syncthreads();
            sscan[tid] += add;
            __syncthreads();
        }
    }
    const int cnte = sscan[255];
    if (slot == 0 && tid == 0) cntg[e] = cnte;
    if (m0 >= cnte) return;
    if (tid < 128) {
        const int s = imin(m0 + tid, cnte - 1);
        int lo = 0, hi = 255;
        #pragma unroll
        for (int itb = 0; itb < 8; ++itb) {
            const int mid = (lo + hi) >> 1;
            if (sscan[mid] > s) hi = mid; else lo = mid + 1;
        }
        const int b = lo;
        const int excl = (b > 0) ? sscan[b - 1] : 0;
        stok[tid] = gtok[b * 64 + e * 8 + (s - excl)];
        swt[tid]  = gwt[b * 64 + e * 8 + (s - excl)];
    }
    __syncthreads();
    if (tile_n == 0 && tid < 128 && (m0 + tid) < cnte)
        invslot[e * 2048 + stok[tid]] = m0 + tid;

    const int lane = tid & 63, wave = tid >> 6;
    const int wm = (wave & 1) * 64, wn = (wave >> 1) * 64;
    const int quad = lane >> 4, l16 = lane & 15;
    const int srow = tid >> 2;
    const int soff = ((tid & 3) ^ ((tid >> 3) & 3)) * 8;

    const int tok0 = stok[srow];
    const int tok1 = stok[64 + srow];
    float cw[4][4];
    #pragma unroll
    for (int i = 0; i < 4; ++i)
        #pragma unroll
        for (int r = 0; r < 4; ++r)
            cw[i][r] = swt[wm + i * 16 + quad * 4 + r];

    const unsigned short* Ar0 = A + tok0 * 512 + soff;
    const unsigned short* Ar1 = A + tok1 * 512 + soff;
    const unsigned short* Bg = w1p + (e * 1024 + np) * 512;
    const unsigned short* Bg0 = Bg + srow * 512 + soff;
    const unsigned short* Bg1 = Bg + (64 + srow) * 512 + soff;
    const unsigned short* Bl0 = Bg0 + 512 * 512;
    const unsigned short* Bl1 = Bg1 + 512 * 512;

    int rA[4], rB[4];
    #pragma unroll
    for (int i = 0; i < 4; ++i) {
        rA[i] = lsw(wm + i * 16 + l16, quad) * 8;
        rB[i] = lsw(wn + i * 16 + l16, quad) * 8;
    }

    f32x4 accG[4][4], accL[4][4];
    #pragma unroll
    for (int i = 0; i < 4; ++i)
        #pragma unroll
        for (int j = 0; j < 4; ++j) {
            f32x4 z = {0.f, 0.f, 0.f, 0.f};
            accG[i][j] = z; accL[i][j] = z;
        }

#define STAGE1(s, k0) do { \
    GLL16(Ar0 + (k0), tA[s] + tid * 8); \
    GLL16(Ar1 + (k0), tA[s] + (tid + 256) * 8); \
    GLL16(Bg0 + (k0), tBg[s] + tid * 8); \
    GLL16(Bg1 + (k0), tBg[s] + (tid + 256) * 8); \
    GLL16(Bl0 + (k0), tBl[s] + tid * 8); \
    GLL16(Bl1 + (k0), tBl[s] + (tid + 256) * 8); \
} while (0)

    STAGE1(0, 0);
    STAGE1(1, 32);
    #pragma unroll
    for (int kt = 0; kt < 16; ++kt) {
        const int cur = kt & 1;
        if (kt < 15) asm volatile("s_waitcnt vmcnt(6)" ::: "memory");
        else         asm volatile("s_waitcnt vmcnt(0)" ::: "memory");
        asm volatile("s_barrier" ::: "memory");
        bf16x8 af[4], bg[4], bl[4];
        #pragma unroll
        for (int i = 0; i < 4; ++i) {
            af[i] = *(const bf16x8*)(tA[cur] + rA[i]);
            bg[i] = *(const bf16x8*)(tBg[cur] + rB[i]);
            bl[i] = *(const bf16x8*)(tBl[cur] + rB[i]);
        }
        asm volatile("s_waitcnt lgkmcnt(0)" ::: "memory");
        asm volatile("s_barrier" ::: "memory");
        if (kt < 14) STAGE1(cur, (kt + 2) * 32);
        #pragma unroll
        for (int i = 0; i < 4; ++i)
            #pragma unroll
            for (int j = 0; j < 4; ++j) {
                accG[i][j] = __builtin_amdgcn_mfma_f32_16x16x32_bf16(af[i], bg[j], accG[i][j], 0, 0, 0);
                accL[i][j] = __builtin_amdgcn_mfma_f32_16x16x32_bf16(af[i], bl[j], accL[i][j], 0, 0, 0);
            }
    }
#undef STAGE1

    #pragma unroll
    for (int j = 0; j < 4; ++j) {
        const int colp = np + wn + j * 16 + l16;
        const float bgv = b1[e * 1024 + 2 * colp];
        const float blv = b1[e * 1024 + 2 * colp + 1];
        #pragma unroll
        for (int i = 0; i < 4; ++i) {
            const int sb = m0 + wm + i * 16 + quad * 4;
            #pragma unroll
            for (int r = 0; r < 4; ++r) {
                const int s = sb + r;
                if (s < cnte) {
                    float g2 = fminf(fmaxf(accG[i][j][r] + bgv, -LIMIT), LIMIT);
                    float l2 = fminf(fmaxf(accL[i][j][r] + blv, -LIMIT), LIMIT);
                    float a = g2 / (1.f + __expf(-ALPHA * g2)) + l2 + 1.f;
                    a *= cw[i][r];
                    As[e * 1048576 + s * 512 + colp] = f2bf(a);
                }
            }
        }
    }
}

// ---------------------------------------------------------------------------
// GEMM2 (routed): grid 512 = 8e x 16m x 4n, XCD = e. Plain fp32 stores into
// compact y[8][2048][512] — NO atomics. Garbage tail rows never read.
// ---------------------------------------------------------------------------
__global__ __launch_bounds__(256, 2) void gemm2(
    const unsigned short* __restrict__ As,  // [8][2048][512] compact
    const unsigned short* __restrict__ w2b, // [8][512][512]
    const int* __restrict__ cntg,           // [8]
    float* __restrict__ y)                  // [8][2048][512] fp32
{
    __shared__ unsigned short tA[2][4096];
    __shared__ unsigned short tB[2][4096];
    const int bx = blockIdx.x;
    const int tid = threadIdx.x;
    const int e = bx & 7;
    const int slot = bx >> 3;
    const int tile_m = slot >> 2, tile_n = slot & 3;
    const int m0 = tile_m * 128, n0 = tile_n * 128;
    const int cnte = cntg[e];
    if (m0 >= cnte) return;

    const int lane = tid & 63, wave = tid >> 6;
    const int wm = (wave & 1) * 64, wn = (wave >> 1) * 64;
    const int quad = lane >> 4, l16 = lane & 15;
    const int srow = tid >> 2;
    const int soff = ((tid & 3) ^ ((tid >> 3) & 3)) * 8;

    const unsigned short* Ar0 = As + e * 1048576 + (m0 + srow) * 512 + soff;
    const unsigned short* Ar1 = As + e * 1048576 + (m0 + 64 + srow) * 512 + soff;
    const unsigned short* Bb  = w2b + e * 262144;
    const unsigned short* Br0 = Bb + (n0 + srow) * 512 + soff;
    const unsigned short* Br1 = Bb + (n0 + 64 + srow) * 512 + soff;

    int rA[4], rB[4];
    #pragma unroll
    for (int i = 0; i < 4; ++i) {
        rA[i] = lsw(wm + i * 16 + l16, quad) * 8;
        rB[i] = lsw(wn + i * 16 + l16, quad) * 8;
    }

    f32x4 acc[4][4];
    #pragma unroll
    for (int i = 0; i < 4; ++i)
        #pragma unroll
        for (int j = 0; j < 4; ++j) { f32x4 z = {0.f, 0.f, 0.f, 0.f}; acc[i][j] = z; }

#define STAGE2(s, k0) do { \
    GLL16(Ar0 + (k0), tA[s] + tid * 8); \
    GLL16(Ar1 + (k0), tA[s] + (tid + 256) * 8); \
    GLL16(Br0 + (k0), tB[s] + tid * 8); \
    GLL16(Br1 + (k0), tB[s] + (tid + 256) * 8); \
} while (0)

    STAGE2(0, 0);
    STAGE2(1, 32);
    #pragma unroll
    for (int kt = 0; kt < 16; ++kt) {
        const int cur = kt & 1;
        if (kt < 15) asm volatile("s_waitcnt vmcnt(4)" ::: "memory");
        else         asm volatile("s_waitcnt vmcnt(0)" ::: "memory");
        asm volatile("s_barrier" ::: "memory");
        bf16x8 af[4], bf[4];
        #pragma unroll
        for (int i = 0; i < 4; ++i) {
            af[i] = *(const bf16x8*)(tA[cur] + rA[i]);
            bf[i] = *(const bf16x8*)(tB[cur] + rB[i]);
        }
        asm volatile("s_waitcnt lgkmcnt(0)" ::: "memory");
        asm volatile("s_barrier" ::: "memory");
        if (kt < 14) STAGE2(cur, (kt + 2) * 32);
        #pragma unroll
        for (int i = 0; i < 4; ++i)
            #pragma unroll
            for (int j = 0; j < 4; ++j)
                acc[i][j] = __builtin_amdgcn_mfma_f32_16x16x32_bf16(af[i], bf[j], acc[i][j], 0, 0, 0);
    }
#undef STAGE2

    float* yb = y + e * 1048576;
    #pragma unroll
    for (int i = 0; i < 4; ++i) {
        const int sb = m0 + wm + i * 16 + quad * 4;
        #pragma unroll
        for (int r = 0; r < 4; ++r) {
            const int s = sb + r;
            #pragma unroll
            for (int j = 0; j < 4; ++j) {
                const int col = n0 + wn + j * 16 + l16;
                yb[s * 512 + col] = acc[i][j][r];
            }
        }
    }
}

// ---------------------------------------------------------------------------
// combine: out[t] = x[t] + sum_k ( y[e_k][slot_k] + c_k * b2[e_k] ).
// grid 256 x 256 thr, wave = 2 tokens. Single write of out, no atomics.
// ---------------------------------------------------------------------------
__global__ __launch_bounds__(256) void combine_kernel(
    const float* __restrict__ x,
    const float* __restrict__ b2,            // [8][512]
    const float* __restrict__ y,             // [8][2048][512]
    const int* __restrict__ invslot,         // [8][2048]
    const unsigned int* __restrict__ esel,   // [2048]
    const float* __restrict__ cw4,           // [2048][4]
    float* __restrict__ out)
{
    const int tid = threadIdx.x;
    const int lane = tid & 63, wave = tid >> 6;
    #pragma unroll
    for (int it = 0; it < 2; ++it) {
        const int t = blockIdx.x * 8 + wave * 2 + it;
        const float4* xr = (const float4*)(x + t * 512);
        float4 o0 = xr[lane * 2];
        float4 o1 = xr[lane * 2 + 1];
        const unsigned sel = esel[t];
        float4 cwv = ((const float4*)cw4)[t];
        const float cws[4] = { cwv.x, cwv.y, cwv.z, cwv.w };
        #pragma unroll
        for (int k = 0; k < 4; ++k) {
            const int e = (sel >> (8 * k)) & 255;
            const int s = invslot[e * 2048 + t];
            const float4* yr = (const float4*)(y + (e * 2048 + s) * 512);
            float4 y0 = yr[lane * 2], y1 = yr[lane * 2 + 1];
            const float4* br = (const float4*)(b2 + e * 512);
            float4 b0 = br[lane * 2], bb1 = br[lane * 2 + 1];
            const float c = cws[k];
            o0.x += y0.x + c * b0.x; o0.y += y0.y + c * b0.y;
            o0.z += y0.z + c * b0.z; o0.w += y0.w + c * b0.w;
            o1.x += y1.x + c * bb1.x; o1.y += y1.y + c * bb1.y;
            o1.z += y1.z + c * bb1.z; o1.w += y1.w + c * bb1.w;
        }
        float4* orow = (float4*)(out + t * 512);
        orow[lane * 2] = o0; orow[lane * 2 + 1] = o1;
    }
}

// ---------------------------------------------------------------------------
extern "C" void kernel_launch(void* const* d_in, const int* in_sizes, int n_in,
                              void* d_out, int out_size, void* d_ws, size_t ws_size,
                              hipStream_t stream)
{
    (void)in_sizes; (void)n_in; (void)out_size; (void)ws_size;
    const float* x          = (const float*)d_in[0];
    const float* norm_scale = (const float*)d_in[1];
    const float* gate_w     = (const float*)d_in[2];
    const float* gate_b     = (const float*)d_in[3];
    const float* mlp1_w     = (const float*)d_in[4];
    const float* mlp1_b     = (const float*)d_in[5];
    const float* mlp2_w     = (const float*)d_in[6];
    const float* mlp2_b     = (const float*)d_in[7];
    float* out = (float*)d_out;

    char* ws = (char*)d_ws;
    unsigned short* w1p   = (unsigned short*)(ws);              // 8,388,608
    unsigned short* w2b   = (unsigned short*)(ws + 8388608);    // 4,194,304
    unsigned short* tbf   = (unsigned short*)(ws + 12582912);   // 2,097,152
    unsigned short* As    = (unsigned short*)(ws + 14680064);   // 16,777,216
    float*          y     = (float*)(ws + 31457280);            // 33,554,432
    float*          paux  = (float*)(ws + 65011712);            // 49,152
    int*            pcnt  = (int*)(ws + 65060864);              // 8,192
    int*            gtok  = (int*)(ws + 65069056);              // 65,536
    float*          gwt   = (float*)(ws + 65134592);            // 65,536
    unsigned int*   esel  = (unsigned int*)(ws + 65200128);     // 8,192
    float*          cw4   = (float*)(ws + 65208320);            // 32,768
    int*            invsl = (int*)(ws + 65241088);              // 65,536
    int*            cntg  = (int*)(ws + 65306624);              // 32

    prep_kernel<<<4352, 256, 0, stream>>>(mlp1_w, w1p,
                                          x, norm_scale, gate_w, gate_b,
                                          tbf, pcnt, gtok, gwt, esel, cw4, paux);
    gemm1_swiglu<<<2561, 256, 0, stream>>>(tbf, w1p, mlp1_b, pcnt, gtok, gwt,
                                           As, cntg, invsl, paux,
                                           out + 2048 * 512, mlp2_w, w2b);
    gemm2<<<512, 256, 0, stream>>>(As, w2b, cntg, y);
    combine_kernel<<<256, 256, 0, stream>>>(x, mlp2_b, y, invsl, esel, cw4, out);
}

// Round 12
// 143.378 us; speedup vs baseline: 1.0723x; 1.0058x over previous
//
#include <hip/hip_runtime.h>
#include <stdint.h>

#define ALPHA 1.702f
#define LIMIT 7.0f

typedef float f32x4 __attribute__((ext_vector_type(4)));
typedef __bf16 bf16x8 __attribute__((ext_vector_type(8)));

static __device__ __forceinline__ unsigned short f2bf(float f) {
    union { float f; uint32_t u; } v; v.f = f;
    uint32_t u = v.u;
    return (unsigned short)((u + 0x7FFFu + ((u >> 16) & 1u)) >> 16);
}
static __device__ __forceinline__ float bflo(uint32_t w) {
    union { uint32_t u; float f; } v; v.u = w << 16; return v.f;
}
static __device__ __forceinline__ float bfhi(uint32_t w) {
    union { uint32_t u; float f; } v; v.u = w & 0xffff0000u; return v.f;
}
static __device__ __forceinline__ int imin(int a, int b) { return a < b ? a : b; }

#define GLL16(GP, LP) __builtin_amdgcn_global_load_lds( \
    (const __attribute__((address_space(1))) void*)(GP), \
    (__attribute__((address_space(3))) void*)(LP), 16, 0, 0)

// Conflict-free LDS swizzle (R3-verified: SQ_LDS_BANK_CONFLICT = 0).
static __device__ __forceinline__ int lsw(int row, int kc) {
    return row * 4 + (kc ^ ((row >> 1) & 3));
}

// ---------------------------------------------------------------------------
// prep: blocks [0,2048): fp32->bf16 W1 convert (glu/lin split, 2 f4/thread).
//       blocks [2048,2304): gate -> t_bf, pcnt/gtok/gwt, esel/cw4, paux.
// ---------------------------------------------------------------------------
__global__ __launch_bounds__(256) void prep_kernel(
    const float* __restrict__ w1,
    unsigned short* __restrict__ w1p,
    const float* __restrict__ x,
    const float* __restrict__ norm_scale,
    const float* __restrict__ gate_w,
    const float* __restrict__ gate_b,
    unsigned short* __restrict__ t_bf,
    int* __restrict__ pcnt,        // [256][8]
    int* __restrict__ gtok,        // [256][8][8]
    float* __restrict__ gwt,       // [256][8][8]
    unsigned int* __restrict__ esel, // [2048] packed 4x expert id
    float* __restrict__ cw4,       // [2048][4]
    float* __restrict__ paux)      // [256][48]
{
    __shared__ float red[4][48];
    __shared__ int   ltok[8][8];
    __shared__ float lwt[8][8];
    __shared__ int   lcnt[8];
    if (blockIdx.x < 2048) {
        #pragma unroll
        for (int k = 0; k < 2; ++k) {
            const int i4 = (blockIdx.x * 2 + k) * 256 + threadIdx.x; // < 1048576
            const int e = i4 >> 17;
            const int rem = i4 & 131071;
            const int r = rem >> 7;
            const int c = rem & 127;
            const int src = (r < 512) ? (2 * r) : (2 * (r - 512) + 1);
            float4 v = ((const float4*)w1)[(e << 17) + (src << 7) + c];
            ushort4 o = { f2bf(v.x), f2bf(v.y), f2bf(v.z), f2bf(v.w) };
            ((ushort4*)w1p)[i4] = o;
        }
        return;
    }
    const int bid = blockIdx.x - 2048;
    const int wave = threadIdx.x >> 6;
    const int lane = threadIdx.x & 63;
    if (threadIdx.x < 8) lcnt[threadIdx.x] = 0;
    __syncthreads();

    float accP[8], accI[8], accC[32];
    #pragma unroll
    for (int e = 0; e < 8; ++e) { accP[e] = 0.f; accI[e] = 0.f; }
    #pragma unroll
    for (int i = 0; i < 32; ++i) accC[i] = 0.f;

    #pragma unroll
    for (int it = 0; it < 2; ++it) {
        const int t = bid * 8 + wave * 2 + it;
        const float4* xr = (const float4*)(x + t * 512);
        float4 x0 = xr[lane * 2];
        float4 x1 = xr[lane * 2 + 1];
        float ss = x0.x*x0.x + x0.y*x0.y + x0.z*x0.z + x0.w*x0.w
                 + x1.x*x1.x + x1.y*x1.y + x1.z*x1.z + x1.w*x1.w;
        #pragma unroll
        for (int off = 32; off > 0; off >>= 1) ss += __shfl_xor(ss, off, 64);
        const float rstd = rsqrtf(ss * (1.f / 512.f) + 1e-6f);
        const float4* sr = (const float4*)norm_scale;
        float4 s0 = sr[lane * 2], s1 = sr[lane * 2 + 1];
        float tv[8];
        tv[0] = x0.x * rstd * s0.x; tv[1] = x0.y * rstd * s0.y;
        tv[2] = x0.z * rstd * s0.z; tv[3] = x0.w * rstd * s0.w;
        tv[4] = x1.x * rstd * s1.x; tv[5] = x1.y * rstd * s1.y;
        tv[6] = x1.z * rstd * s1.z; tv[7] = x1.w * rstd * s1.w;
        uint32_t p0 = (uint32_t)f2bf(tv[0]) | ((uint32_t)f2bf(tv[1]) << 16);
        uint32_t p1 = (uint32_t)f2bf(tv[2]) | ((uint32_t)f2bf(tv[3]) << 16);
        uint32_t p2 = (uint32_t)f2bf(tv[4]) | ((uint32_t)f2bf(tv[5]) << 16);
        uint32_t p3 = (uint32_t)f2bf(tv[6]) | ((uint32_t)f2bf(tv[7]) << 16);
        uint4 pk; pk.x = p0; pk.y = p1; pk.z = p2; pk.w = p3;
        ((uint4*)(t_bf + t * 512))[lane] = pk;
        float le[8];
        #pragma unroll
        for (int e = 0; e < 8; ++e) {
            const float4* gw = (const float4*)(gate_w + e * 512);
            float4 g0 = gw[lane * 2], g1 = gw[lane * 2 + 1];
            float d = tv[0]*g0.x + tv[1]*g0.y + tv[2]*g0.z + tv[3]*g0.w
                    + tv[4]*g1.x + tv[5]*g1.y + tv[6]*g1.z + tv[7]*g1.w;
            #pragma unroll
            for (int off = 32; off > 0; off >>= 1) d += __shfl_xor(d, off, 64);
            le[e] = d + gate_b[e];
        }
        float mx = le[0];
        #pragma unroll
        for (int e = 1; e < 8; ++e) mx = fmaxf(mx, le[e]);
        float pe[8], se = 0.f;
        #pragma unroll
        for (int e = 0; e < 8; ++e) { pe[e] = __expf(le[e] - mx); se += pe[e]; }
        const float sinv = 1.f / se;
        #pragma unroll
        for (int e = 0; e < 8; ++e) pe[e] *= sinv;
        unsigned picked = 0;
        int ik[4]; float wk[4];
        #pragma unroll
        for (int k = 0; k < 4; ++k) {
            float bv = -1.f; int bi = 0;
            #pragma unroll
            for (int e = 0; e < 8; ++e)
                if (!(picked & (1u << e)) && pe[e] > bv) { bv = pe[e]; bi = e; }
            ik[k] = bi; wk[k] = bv; picked |= (1u << bi);
        }
        const float winv = 1.f / (wk[0] + wk[1] + wk[2] + wk[3]);
        float nw[4];
        #pragma unroll
        for (int k = 0; k < 4; ++k) nw[k] = wk[k] * winv;
        if (lane == 0) {
            #pragma unroll
            for (int k = 0; k < 4; ++k) {
                const int e = ik[k];
                const int pos = atomicAdd(&lcnt[e], 1);   // LDS atomic
                ltok[e][pos] = t; lwt[e][pos] = nw[k];
            }
            esel[t] = (unsigned)ik[0] | ((unsigned)ik[1] << 8)
                    | ((unsigned)ik[2] << 16) | ((unsigned)ik[3] << 24);
            float4 cwv; cwv.x = nw[0]; cwv.y = nw[1]; cwv.z = nw[2]; cwv.w = nw[3];
            ((float4*)cw4)[t] = cwv;
        }
        #pragma unroll
        for (int e = 0; e < 8; ++e) { accP[e] += pe[e]; accI[e] += le[e]; }
        #pragma unroll
        for (int k = 0; k < 4; ++k)
            #pragma unroll
            for (int e = 0; e < 8; ++e)
                accC[k * 8 + e] += (ik[k] == e) ? 1.f : 0.f;
    }
    if (lane == 0) {
        #pragma unroll
        for (int e = 0; e < 8; ++e) { red[wave][e] = accP[e]; red[wave][8 + e] = accI[e]; }
        #pragma unroll
        for (int i = 0; i < 32; ++i) red[wave][16 + i] = accC[i];
    }
    __syncthreads();
    if (threadIdx.x < 8) pcnt[bid * 8 + threadIdx.x] = lcnt[threadIdx.x];
    if (threadIdx.x < 64) {
        const int e = threadIdx.x >> 3, i = threadIdx.x & 7;
        if (i < lcnt[e]) {
            gtok[bid * 64 + threadIdx.x] = ltok[e][i];
            gwt[bid * 64 + threadIdx.x]  = lwt[e][i];
        }
    }
    if (threadIdx.x < 48) {
        paux[bid * 48 + threadIdx.x] =
            red[0][threadIdx.x] + red[1][threadIdx.x]
          + red[2][threadIdx.x] + red[3][threadIdx.x];
    }
}

// ---------------------------------------------------------------------------
// GEMM1 (routed) + swiglu*wcoef. grid 1025:
//   blocks 0..511: 8e x 16m x 4n compute tiles (XCD = e), publish cntg and
//                  invslot (tile_n==0), write compact As.
//   block 512: aux loss. blocks 513..1024: W2 fp32->bf16 convert shadow
//   (4 float4/thread; runs as gemm1 compute blocks retire).
// ---------------------------------------------------------------------------
__global__ __launch_bounds__(256, 2) void gemm1_swiglu(
    const unsigned short* __restrict__ A,    // t_bf [2048][512]
    const unsigned short* __restrict__ w1p,  // [8][1024][512] glu/lin split
    const float* __restrict__ b1,            // [8][1024] interleaved
    const int* __restrict__ pcnt,            // [256][8]
    const int* __restrict__ gtok,            // [256][8][8]
    const float* __restrict__ gwt,           // [256][8][8]
    unsigned short* __restrict__ As,         // [8][2048][512] compact
    int* __restrict__ cntg,                  // [8]
    int* __restrict__ invslot,               // [8][2048] token -> slot
    const float* __restrict__ paux,          // [256][48]
    float* __restrict__ aux_out,
    const float* __restrict__ w2,            // fp32 [8][512][512]
    unsigned short* __restrict__ w2b)        // bf16 out
{
    if (blockIdx.x == 512) {
        __shared__ float sred[4][48];
        const int wv = threadIdx.x >> 6, ln = threadIdx.x & 63;
        if (ln < 48) {
            float s = 0.f;
            for (int b = 0; b < 64; ++b) s += paux[(wv * 64 + b) * 48 + ln];
            sred[wv][ln] = s;
        }
        __syncthreads();
        if (threadIdx.x == 0) {
            float imp[8], sl = 0.f;
            #pragma unroll
            for (int e = 0; e < 8; ++e) {
                float a0 = sred[0][e] + sred[1][e] + sred[2][e] + sred[3][e];
                float P = a0 * (1.f / 2048.f);
                imp[e] = sred[0][8+e] + sred[1][8+e] + sred[2][8+e] + sred[3][8+e];
                float c0 = sred[0][16+e] + sred[1][16+e] + sred[2][16+e] + sred[3][16+e];
                float c1 = sred[0][24+e] + sred[1][24+e] + sred[2][24+e] + sred[3][24+e];
                float c2 = sred[0][32+e] + sred[1][32+e] + sred[2][32+e] + sred[3][32+e];
                float c3 = sred[0][40+e] + sred[1][40+e] + sred[2][40+e] + sred[3][40+e];
                float D = (16.f * c0 + 8.f * c1 + 4.f * c2 + 2.f * c3) * (1.f / 8192.f);
                sl += P * D;
            }
            float loss_load = 0.01f * 8.f * sl;
            float mean = 0.f;
            #pragma unroll
            for (int e = 0; e < 8; ++e) mean += imp[e];
            mean *= 0.125f;
            float var = 0.f;
            #pragma unroll
            for (int e = 0; e < 8; ++e) { float d = imp[e] - mean; var += d * d; }
            var *= (1.f / 7.f);
            float cv = sqrtf(var) / (mean + 1e-6f);
            *aux_out = loss_load + 0.01f * cv * cv;
        }
        return;
    }
    if (blockIdx.x > 512) {
        const int base = (blockIdx.x - 513) * 1024 + threadIdx.x;
        #pragma unroll
        for (int k = 0; k < 4; ++k) {
            const int i2 = base + k * 256;      // < 524288
            float4 v = ((const float4*)w2)[i2];
            ushort4 o = { f2bf(v.x), f2bf(v.y), f2bf(v.z), f2bf(v.w) };
            ((ushort4*)w2b)[i2] = o;
        }
        return;
    }
    __shared__ unsigned short tA[2][4096];
    __shared__ unsigned short tBg[2][4096];
    __shared__ unsigned short tBl[2][4096];
    __shared__ int sscan[256];
    __shared__ int stok[128];
    __shared__ float swt[128];
    const int bx = blockIdx.x;
    const int tid = threadIdx.x;
    const int e = bx & 7;
    const int slot = bx >> 3;
    const int tile_m = slot >> 2, tile_n = slot & 3;
    const int m0 = tile_m * 128, np = tile_n * 128;

    // route preamble: scan pcnt[:,e], build 128-slot token/weight table
    {
        const int v = pcnt[tid * 8 + e];
        sscan[tid] = v;
        __syncthreads();
        for (int ofs = 1; ofs < 256; ofs <<= 1) {
            int add = (tid >= ofs) ? sscan[tid - ofs] : 0;
            __syncthreads();
            sscan[tid] += add;
            __syncthreads();
        }
    }
    const int cnte = sscan[255];
    if (slot == 0 && tid == 0) cntg[e] = cnte;
    if (m0 >= cnte) return;
    if (tid < 128) {
        const int s = imin(m0 + tid, cnte - 1);
        int lo = 0, hi = 255;
        #pragma unroll
        for (int itb = 0; itb < 8; ++itb) {
            const int mid = (lo + hi) >> 1;
            if (sscan[mid] > s) hi = mid; else lo = mid + 1;
        }
        const int b = lo;
        const int excl = (b > 0) ? sscan[b - 1] : 0;
        stok[tid] = gtok[b * 64 + e * 8 + (s - excl)];
        swt[tid]  = gwt[b * 64 + e * 8 + (s - excl)];
    }
    __syncthreads();
    if (tile_n == 0 && tid < 128 && (m0 + tid) < cnte)
        invslot[e * 2048 + stok[tid]] = m0 + tid;

    const int lane = tid & 63, wave = tid >> 6;
    const int wm = (wave & 1) * 64, wn = (wave >> 1) * 64;
    const int quad = lane >> 4, l16 = lane & 15;
    const int srow = tid >> 2;
    const int soff = ((tid & 3) ^ ((tid >> 3) & 3)) * 8;

    const int tok0 = stok[srow];
    const int tok1 = stok[64 + srow];
    float cw[4][4];
    #pragma unroll
    for (int i = 0; i < 4; ++i)
        #pragma unroll
        for (int r = 0; r < 4; ++r)
            cw[i][r] = swt[wm + i * 16 + quad * 4 + r];

    const unsigned short* Ar0 = A + tok0 * 512 + soff;
    const unsigned short* Ar1 = A + tok1 * 512 + soff;
    const unsigned short* Bg = w1p + (e * 1024 + np) * 512;
    const unsigned short* Bg0 = Bg + srow * 512 + soff;
    const unsigned short* Bg1 = Bg + (64 + srow) * 512 + soff;
    const unsigned short* Bl0 = Bg0 + 512 * 512;
    const unsigned short* Bl1 = Bg1 + 512 * 512;

    int rA[4], rB[4];
    #pragma unroll
    for (int i = 0; i < 4; ++i) {
        rA[i] = lsw(wm + i * 16 + l16, quad) * 8;
        rB[i] = lsw(wn + i * 16 + l16, quad) * 8;
    }

    f32x4 accG[4][4], accL[4][4];
    #pragma unroll
    for (int i = 0; i < 4; ++i)
        #pragma unroll
        for (int j = 0; j < 4; ++j) {
            f32x4 z = {0.f, 0.f, 0.f, 0.f};
            accG[i][j] = z; accL[i][j] = z;
        }

#define STAGE1(s, k0) do { \
    GLL16(Ar0 + (k0), tA[s] + tid * 8); \
    GLL16(Ar1 + (k0), tA[s] + (tid + 256) * 8); \
    GLL16(Bg0 + (k0), tBg[s] + tid * 8); \
    GLL16(Bg1 + (k0), tBg[s] + (tid + 256) * 8); \
    GLL16(Bl0 + (k0), tBl[s] + tid * 8); \
    GLL16(Bl1 + (k0), tBl[s] + (tid + 256) * 8); \
} while (0)

    STAGE1(0, 0);
    STAGE1(1, 32);
    #pragma unroll
    for (int kt = 0; kt < 16; ++kt) {
        const int cur = kt & 1;
        if (kt < 15) asm volatile("s_waitcnt vmcnt(6)" ::: "memory");
        else         asm volatile("s_waitcnt vmcnt(0)" ::: "memory");
        asm volatile("s_barrier" ::: "memory");
        bf16x8 af[4], bg[4], bl[4];
        #pragma unroll
        for (int i = 0; i < 4; ++i) {
            af[i] = *(const bf16x8*)(tA[cur] + rA[i]);
            bg[i] = *(const bf16x8*)(tBg[cur] + rB[i]);
            bl[i] = *(const bf16x8*)(tBl[cur] + rB[i]);
        }
        asm volatile("s_waitcnt lgkmcnt(0)" ::: "memory");
        asm volatile("s_barrier" ::: "memory");
        if (kt < 14) STAGE1(cur, (kt + 2) * 32);
        #pragma unroll
        for (int i = 0; i < 4; ++i)
            #pragma unroll
            for (int j = 0; j < 4; ++j) {
                accG[i][j] = __builtin_amdgcn_mfma_f32_16x16x32_bf16(af[i], bg[j], accG[i][j], 0, 0, 0);
                accL[i][j] = __builtin_amdgcn_mfma_f32_16x16x32_bf16(af[i], bl[j], accL[i][j], 0, 0, 0);
            }
    }
#undef STAGE1

    #pragma unroll
    for (int j = 0; j < 4; ++j) {
        const int colp = np + wn + j * 16 + l16;
        const float bgv = b1[e * 1024 + 2 * colp];
        const float blv = b1[e * 1024 + 2 * colp + 1];
        #pragma unroll
        for (int i = 0; i < 4; ++i) {
            const int sb = m0 + wm + i * 16 + quad * 4;
            #pragma unroll
            for (int r = 0; r < 4; ++r) {
                const int s = sb + r;
                if (s < cnte) {
                    float g2 = fminf(fmaxf(accG[i][j][r] + bgv, -LIMIT), LIMIT);
                    float l2 = fminf(fmaxf(accL[i][j][r] + blv, -LIMIT), LIMIT);
                    float a = g2 / (1.f + __expf(-ALPHA * g2)) + l2 + 1.f;
                    a *= cw[i][r];
                    As[e * 1048576 + s * 512 + colp] = f2bf(a);
                }
            }
        }
    }
}

// ---------------------------------------------------------------------------
// GEMM2 (routed): grid 512 = 8e x 16m x 4n, XCD = e. Plain bf16 stores into
// compact y[8][2048][512] — NO atomics, half the fp32 write traffic.
// ---------------------------------------------------------------------------
__global__ __launch_bounds__(256, 2) void gemm2(
    const unsigned short* __restrict__ As,  // [8][2048][512] compact
    const unsigned short* __restrict__ w2b, // [8][512][512]
    const int* __restrict__ cntg,           // [8]
    unsigned short* __restrict__ y)         // [8][2048][512] bf16
{
    __shared__ unsigned short tA[2][4096];
    __shared__ unsigned short tB[2][4096];
    const int bx = blockIdx.x;
    const int tid = threadIdx.x;
    const int e = bx & 7;
    const int slot = bx >> 3;
    const int tile_m = slot >> 2, tile_n = slot & 3;
    const int m0 = tile_m * 128, n0 = tile_n * 128;
    const int cnte = cntg[e];
    if (m0 >= cnte) return;

    const int lane = tid & 63, wave = tid >> 6;
    const int wm = (wave & 1) * 64, wn = (wave >> 1) * 64;
    const int quad = lane >> 4, l16 = lane & 15;
    const int srow = tid >> 2;
    const int soff = ((tid & 3) ^ ((tid >> 3) & 3)) * 8;

    const unsigned short* Ar0 = As + e * 1048576 + (m0 + srow) * 512 + soff;
    const unsigned short* Ar1 = As + e * 1048576 + (m0 + 64 + srow) * 512 + soff;
    const unsigned short* Bb  = w2b + e * 262144;
    const unsigned short* Br0 = Bb + (n0 + srow) * 512 + soff;
    const unsigned short* Br1 = Bb + (n0 + 64 + srow) * 512 + soff;

    int rA[4], rB[4];
    #pragma unroll
    for (int i = 0; i < 4; ++i) {
        rA[i] = lsw(wm + i * 16 + l16, quad) * 8;
        rB[i] = lsw(wn + i * 16 + l16, quad) * 8;
    }

    f32x4 acc[4][4];
    #pragma unroll
    for (int i = 0; i < 4; ++i)
        #pragma unroll
        for (int j = 0; j < 4; ++j) { f32x4 z = {0.f, 0.f, 0.f, 0.f}; acc[i][j] = z; }

#define STAGE2(s, k0) do { \
    GLL16(Ar0 + (k0), tA[s] + tid * 8); \
    GLL16(Ar1 + (k0), tA[s] + (tid + 256) * 8); \
    GLL16(Br0 + (k0), tB[s] + tid * 8); \
    GLL16(Br1 + (k0), tB[s] + (tid + 256) * 8); \
} while (0)

    STAGE2(0, 0);
    STAGE2(1, 32);
    #pragma unroll
    for (int kt = 0; kt < 16; ++kt) {
        const int cur = kt & 1;
        if (kt < 15) asm volatile("s_waitcnt vmcnt(4)" ::: "memory");
        else         asm volatile("s_waitcnt vmcnt(0)" ::: "memory");
        asm volatile("s_barrier" ::: "memory");
        bf16x8 af[4], bf[4];
        #pragma unroll
        for (int i = 0; i < 4; ++i) {
            af[i] = *(const bf16x8*)(tA[cur] + rA[i]);
            bf[i] = *(const bf16x8*)(tB[cur] + rB[i]);
        }
        asm volatile("s_waitcnt lgkmcnt(0)" ::: "memory");
        asm volatile("s_barrier" ::: "memory");
        if (kt < 14) STAGE2(cur, (kt + 2) * 32);
        #pragma unroll
        for (int i = 0; i < 4; ++i)
            #pragma unroll
            for (int j = 0; j < 4; ++j)
                acc[i][j] = __builtin_amdgcn_mfma_f32_16x16x32_bf16(af[i], bf[j], acc[i][j], 0, 0, 0);
    }
#undef STAGE2

    unsigned short* yb = y + e * 1048576;
    #pragma unroll
    for (int i = 0; i < 4; ++i) {
        const int sb = m0 + wm + i * 16 + quad * 4;
        #pragma unroll
        for (int r = 0; r < 4; ++r) {
            const int s = sb + r;
            #pragma unroll
            for (int j = 0; j < 4; ++j) {
                const int col = n0 + wn + j * 16 + l16;
                yb[s * 512 + col] = f2bf(acc[i][j][r]);
            }
        }
    }
}

// ---------------------------------------------------------------------------
// combine: out[t] = x[t] + sum_k ( y[e_k][slot_k] + c_k * b2[e_k] ).
// y is bf16: one uint4 per lane covers 8 elements. Single write of out.
// ---------------------------------------------------------------------------
__global__ __launch_bounds__(256) void combine_kernel(
    const float* __restrict__ x,
    const float* __restrict__ b2,            // [8][512]
    const unsigned short* __restrict__ y,    // [8][2048][512] bf16
    const int* __restrict__ invslot,         // [8][2048]
    const unsigned int* __restrict__ esel,   // [2048]
    const float* __restrict__ cw4,           // [2048][4]
    float* __restrict__ out)
{
    const int tid = threadIdx.x;
    const int lane = tid & 63, wave = tid >> 6;
    #pragma unroll
    for (int it = 0; it < 2; ++it) {
        const int t = blockIdx.x * 8 + wave * 2 + it;
        const float4* xr = (const float4*)(x + t * 512);
        float4 o0 = xr[lane * 2];
        float4 o1 = xr[lane * 2 + 1];
        const unsigned sel = esel[t];
        float4 cwv = ((const float4*)cw4)[t];
        const float cws[4] = { cwv.x, cwv.y, cwv.z, cwv.w };
        #pragma unroll
        for (int k = 0; k < 4; ++k) {
            const int e = (sel >> (8 * k)) & 255;
            const int s = invslot[e * 2048 + t];
            uint4 p = ((const uint4*)(y + (e * 2048 + s) * 512))[lane];
            const float4* br = (const float4*)(b2 + e * 512);
            float4 b0 = br[lane * 2], bb1 = br[lane * 2 + 1];
            const float c = cws[k];
            o0.x += bflo(p.x) + c * b0.x;  o0.y += bfhi(p.x) + c * b0.y;
            o0.z += bflo(p.y) + c * b0.z;  o0.w += bfhi(p.y) + c * b0.w;
            o1.x += bflo(p.z) + c * bb1.x; o1.y += bfhi(p.z) + c * bb1.y;
            o1.z += bflo(p.w) + c * bb1.z; o1.w += bfhi(p.w) + c * bb1.w;
        }
        float4* orow = (float4*)(out + t * 512);
        orow[lane * 2] = o0; orow[lane * 2 + 1] = o1;
    }
}

// ---------------------------------------------------------------------------
extern "C" void kernel_launch(void* const* d_in, const int* in_sizes, int n_in,
                              void* d_out, int out_size, void* d_ws, size_t ws_size,
                              hipStream_t stream)
{
    (void)in_sizes; (void)n_in; (void)out_size; (void)ws_size;
    const float* x          = (const float*)d_in[0];
    const float* norm_scale = (const float*)d_in[1];
    const float* gate_w     = (const float*)d_in[2];
    const float* gate_b     = (const float*)d_in[3];
    const float* mlp1_w     = (const float*)d_in[4];
    const float* mlp1_b     = (const float*)d_in[5];
    const float* mlp2_w     = (const float*)d_in[6];
    const float* mlp2_b     = (const float*)d_in[7];
    float* out = (float*)d_out;

    char* ws = (char*)d_ws;
    unsigned short* w1p   = (unsigned short*)(ws);              // 8,388,608
    unsigned short* w2b   = (unsigned short*)(ws + 8388608);    // 4,194,304
    unsigned short* tbf   = (unsigned short*)(ws + 12582912);   // 2,097,152
    unsigned short* As    = (unsigned short*)(ws + 14680064);   // 16,777,216
    unsigned short* y     = (unsigned short*)(ws + 31457280);   // 16,777,216
    float*          paux  = (float*)(ws + 48234496);            // 49,152
    int*            pcnt  = (int*)(ws + 48283648);              // 8,192
    int*            gtok  = (int*)(ws + 48291840);              // 65,536
    float*          gwt   = (float*)(ws + 48357376);            // 65,536
    unsigned int*   esel  = (unsigned int*)(ws + 48422912);     // 8,192
    float*          cw4   = (float*)(ws + 48431104);            // 32,768
    int*            invsl = (int*)(ws + 48463872);              // 65,536
    int*            cntg  = (int*)(ws + 48529408);              // 32

    prep_kernel<<<2304, 256, 0, stream>>>(mlp1_w, w1p,
                                          x, norm_scale, gate_w, gate_b,
                                          tbf, pcnt, gtok, gwt, esel, cw4, paux);
    gemm1_swiglu<<<1025, 256, 0, stream>>>(tbf, w1p, mlp1_b, pcnt, gtok, gwt,
                                           As, cntg, invsl, paux,
                                           out + 2048 * 512, mlp2_w, w2b);
    gemm2<<<512, 256, 0, stream>>>(As, w2b, cntg, y);
    combine_kernel<<<256, 256, 0, stream>>>(x, mlp2_b, y, invsl, esel, cw4, out);
}